// Round 3
// baseline (15323.061 us; speedup 1.0000x reference)
//
#include <hip/hip_runtime.h>
#include <hip/hip_fp16.h>
#include <math.h>

// Problem dims
#define T_STEPS 1024
#define BATCH   128
#define D_IN    256
#define H_DIM   256
#define NCOL    1024   // 4 gates * 256
#define CHUNK   16     // steps per x-precompute chunk
#define K2X     128    // x-part k-pairs
#define K2H     128    // hx-part k-pairs
#define K2REG   64     // hx k-pairs held in VGPRs
#define K2STR   (K2H - K2REG)

typedef _Float16 h2 __attribute__((ext_vector_type(2)));

__device__ __forceinline__ float sigmoidf_(float x) {
    return 1.0f / (1.0f + __expf(-x));
}
__device__ __forceinline__ float tanhf_(float x) {
    float ax = fabsf(x);
    float t = __expf(-2.0f * ax);
    float r = (1.0f - t) / (1.0f + t);
    return copysignf(r, x);
}
__device__ __forceinline__ h2 u2h2(unsigned u) {
    union { unsigned u; h2 h; } v; v.u = u; return v.h;
}
__device__ __forceinline__ unsigned packh2(float a, float b) {
    union { h2 h; unsigned u; } v;
    v.h.x = (_Float16)a; v.h.y = (_Float16)b; return v.u;
}
__device__ __forceinline__ float fdot2_(h2 a, h2 b, float c) {
#if __has_builtin(__builtin_amdgcn_fdot2)
    return __builtin_amdgcn_fdot2(a, b, c, false);
#else
    return fmaf((float)a.x, (float)b.x, fmaf((float)a.y, (float)b.y, c));
#endif
}
__device__ __forceinline__ float2 f2fma(float2 w, float xs, float2 a) {
    a.x = fmaf(w.x, xs, a.x); a.y = fmaf(w.y, xs, a.y); return a;
}

// Pack f16 weight pairs, partitioned:
//   WX2   [128][1024]  x-part (k = 2*k2)
//   WHreg [64][1024]   hx-part k2 in [0,64)   (k = 256 + 2*k2)  -> VGPR-resident
//   WHstr [64][1024]   hx-part k2 in [64,128)                    -> streamed
// j = gate*256 + h.  biasc[1024] fp32.
__global__ void prep_kernel(const float* __restrict__ Wf, const float* __restrict__ Wi,
                            const float* __restrict__ Wg, const float* __restrict__ Wo,
                            const float* __restrict__ bf, const float* __restrict__ bi,
                            const float* __restrict__ bg, const float* __restrict__ bo,
                            unsigned* __restrict__ WX2, unsigned* __restrict__ WHreg,
                            unsigned* __restrict__ WHstr, float* __restrict__ biasc) {
    int idx = blockIdx.x * 256 + threadIdx.x;   // 0 .. 128*1024-1
    int k2 = idx >> 10;
    int j  = idx & 1023;
    int g  = j >> 8;
    int h  = j & 255;
    const float* W = (g == 0) ? Wf : (g == 1) ? Wi : (g == 2) ? Wg : Wo;
    const float* row = W + h * 512;
    WX2[idx] = packh2(row[2 * k2], row[2 * k2 + 1]);
    unsigned hp = packh2(row[256 + 2 * k2], row[256 + 2 * k2 + 1]);
    if (k2 < K2REG) WHreg[k2 * NCOL + j] = hp;
    else            WHstr[(k2 - K2REG) * NCOL + j] = hp;
    if (idx < NCOL) {
        const float* bb = (g == 0) ? bf : (g == 1) ? bi : (g == 2) ? bg : bo;
        biasc[idx] = bb[h];
    }
}

// One WG (512 threads) per batch row. Thread tid owns cols c0=2*tid, c0+1
// (gate = tid>>7, h = (2*tid)&255). 64 k2-pairs of hx-weights live in VGPRs.
__global__ __launch_bounds__(512, 2) void qlstm_kernel(
    const float* __restrict__ x,
    const unsigned* __restrict__ WX2,
    const unsigned* __restrict__ WHreg,
    const unsigned* __restrict__ WHstr,
    const float* __restrict__ biasc,
    const float* __restrict__ estW1, const float* __restrict__ estb1,
    const float* __restrict__ estW2, const float* __restrict__ estb2,
    const float* __restrict__ estW3, const float* __restrict__ estb3,
    float* __restrict__ out)
{
    __shared__ float preb[CHUNK * NCOL];               // 64 KB x-projection chunk
    __shared__ float w1s[4 * 8 * H_DIM];               // 32 KB estW1
    __shared__ float gatesv[4 * H_DIM];                // raw activated gates
    __shared__ __align__(16) unsigned combh2[H_DIM/2]; // hx as packed f16 pairs
    __shared__ float ep[8 * 8];                        // est partials [wave][j]
    __shared__ float sb1[32], sW2[128], sb2[16], sW3[16], sb3[4];
    __shared__ float escale[4];

    const int b    = blockIdx.x;
    const int tid  = threadIdx.x;
    const int lane = tid & 63;
    const int wv   = tid >> 6;
    const int c0   = 2 * tid;
    const int g    = tid >> 7;          // gate of this thread's columns
    const int h0   = c0 & 255;          // h of first column

    // stage est params
    for (int i = tid; i < 4 * 8 * H_DIM; i += 512) w1s[i] = estW1[i];
    if (tid < 32)  sb1[tid] = estb1[tid];
    if (tid < 128) sW2[tid] = estW2[tid];
    if (tid < 16)  sb2[tid] = estb2[tid];
    if (tid < 16)  sW3[tid] = estW3[tid];
    if (tid < 4)   sb3[tid] = estb3[tid];
    if (tid < 128) combh2[tid] = 0u;

    // register-resident hx weights: 64 k2 x 2 cols = 128 VGPRs
    uint2 wreg[K2REG];
    #pragma unroll
    for (int k2 = 0; k2 < K2REG; k2++)
        wreg[k2] = ((const uint2*)WHreg)[k2 * 512 + tid];

    const float2 bias01 = ((const float2*)biasc)[tid];
    float cst0 = 0.f, cst1 = 0.f, hlast0 = 0.f, hlast1 = 0.f;

    __syncthreads();

    #pragma unroll 1
    for (int tc = 0; tc < T_STEPS; tc += CHUNK) {
        // ================= x-projection pre-phase (parallel-in-t) =========
        {
            float2 acc[CHUNK];
            #pragma unroll
            for (int s = 0; s < CHUNK; s++) acc[s] = bias01;
            #pragma unroll 1
            for (int kb = 0; kb < K2X; kb += 4) {       // 4 k2 = 8 k floats
                float2 wlo[4], whi[4];
                #pragma unroll
                for (int q = 0; q < 4; q++) {
                    uint2 wu = ((const uint2*)WX2)[(kb + q) * 512 + tid];
                    h2 p0 = u2h2(wu.x), p1 = u2h2(wu.y);
                    wlo[q] = make_float2((float)p0.x, (float)p1.x);
                    whi[q] = make_float2((float)p0.y, (float)p1.y);
                }
                #pragma unroll
                for (int s = 0; s < CHUNK; s++) {
                    // wave-uniform address -> scalar loads through K$
                    const float4* xr = (const float4*)(x + ((size_t)(tc + s) * BATCH + b) * D_IN);
                    float4 xa = xr[kb >> 1];
                    float4 xb4 = xr[(kb >> 1) + 1];
                    acc[s] = f2fma(wlo[0], xa.x, acc[s]);
                    acc[s] = f2fma(whi[0], xa.y, acc[s]);
                    acc[s] = f2fma(wlo[1], xa.z, acc[s]);
                    acc[s] = f2fma(whi[1], xa.w, acc[s]);
                    acc[s] = f2fma(wlo[2], xb4.x, acc[s]);
                    acc[s] = f2fma(whi[2], xb4.y, acc[s]);
                    acc[s] = f2fma(wlo[3], xb4.z, acc[s]);
                    acc[s] = f2fma(whi[3], xb4.w, acc[s]);
                }
            }
            #pragma unroll
            for (int s = 0; s < CHUNK; s++)
                *(float2*)&preb[s * NCOL + c0] = acc[s];
        }
        __syncthreads();

        // ================= CHUNK recurrence steps =========================
        #pragma unroll 1
        for (int s = 0; s < CHUNK; s++) {
            const int t = tc + s;
            float2 pv = *(const float2*)&preb[s * NCOL + c0];
            float a0 = pv.x, a1 = pv.y;

            // hx GEMM, register portion (k2 0..63)
            #pragma unroll
            for (int k4 = 0; k4 < K2REG / 4; k4++) {
                uint4 cv = *((const uint4*)combh2 + k4);   // broadcast
                h2 c0h = u2h2(cv.x), c1h = u2h2(cv.y), c2h = u2h2(cv.z), c3h = u2h2(cv.w);
                a0 = fdot2_(u2h2(wreg[4*k4+0].x), c0h, a0);
                a1 = fdot2_(u2h2(wreg[4*k4+0].y), c0h, a1);
                a0 = fdot2_(u2h2(wreg[4*k4+1].x), c1h, a0);
                a1 = fdot2_(u2h2(wreg[4*k4+1].y), c1h, a1);
                a0 = fdot2_(u2h2(wreg[4*k4+2].x), c2h, a0);
                a1 = fdot2_(u2h2(wreg[4*k4+2].y), c2h, a1);
                a0 = fdot2_(u2h2(wreg[4*k4+3].x), c3h, a0);
                a1 = fdot2_(u2h2(wreg[4*k4+3].y), c3h, a1);
            }
            // hx GEMM, streamed portion (k2 64..127, re-read from L2 each step)
            {
                const uint2* wsp = (const uint2*)WHstr + tid;
                #pragma unroll
                for (int k4 = 0; k4 < K2STR / 4; k4++) {
                    uint4 cv = *((const uint4*)combh2 + (K2REG / 4) + k4);
                    uint2 w0 = wsp[(4*k4+0) * 512];
                    uint2 w1 = wsp[(4*k4+1) * 512];
                    uint2 w2 = wsp[(4*k4+2) * 512];
                    uint2 w3 = wsp[(4*k4+3) * 512];
                    h2 c0h = u2h2(cv.x), c1h = u2h2(cv.y), c2h = u2h2(cv.z), c3h = u2h2(cv.w);
                    a0 = fdot2_(u2h2(w0.x), c0h, a0);
                    a1 = fdot2_(u2h2(w0.y), c0h, a1);
                    a0 = fdot2_(u2h2(w1.x), c1h, a0);
                    a1 = fdot2_(u2h2(w1.y), c1h, a1);
                    a0 = fdot2_(u2h2(w2.x), c2h, a0);
                    a1 = fdot2_(u2h2(w2.y), c2h, a1);
                    a0 = fdot2_(u2h2(w3.x), c3h, a0);
                    a1 = fdot2_(u2h2(w3.y), c3h, a1);
                }
            }

            // activation (gate 2 = tanh; wave-uniform branch)
            float v0, v1;
            if (g == 2) { v0 = tanhf_(a0); v1 = tanhf_(a1); }
            else        { v0 = sigmoidf_(a0); v1 = sigmoidf_(a1); }
            *(float2*)&gatesv[g * 256 + h0] = make_float2(v0, v1);

            // est layer-1 partial: wave wv covers gate wv>>1, h-half wv&1
            {
                const int gw = wv >> 1;
                const float* w1p = &w1s[gw * 2048 + h0];
                float p[8];
                #pragma unroll
                for (int j = 0; j < 8; j++) {
                    float2 wj = *(const float2*)&w1p[j * 256];
                    float sj = fmaf(v0, wj.x, v1 * wj.y);
                    #pragma unroll
                    for (int m = 1; m < 64; m <<= 1) sj += __shfl_xor(sj, m, 64);
                    p[j] = sj;
                }
                if (lane == 0) {
                    *(float4*)&ep[wv * 8]     = make_float4(p[0], p[1], p[2], p[3]);
                    *(float4*)&ep[wv * 8 + 4] = make_float4(p[4], p[5], p[6], p[7]);
                }
            }
            __syncthreads();   // partials + gatesv visible

            // est layers on wave 0 (lanes redundant where out-of-role)
            if (wv == 0) {
                const int gg = (lane >> 3) & 3, jj = lane & 7;
                float h1v = tanhf_(ep[(gg * 2) * 8 + jj] + ep[(gg * 2 + 1) * 8 + jj]
                                   + sb1[gg * 8 + jj]);        // valid lanes 0..31
                const int g2 = (lane >> 2) & 3, j2 = lane & 3;
                float s2 = sb2[g2 * 4 + j2];
                #pragma unroll
                for (int q = 0; q < 8; q++)
                    s2 = fmaf(__shfl(h1v, g2 * 8 + q, 64), sW2[g2 * 32 + j2 * 8 + q], s2);
                float h2v = tanhf_(s2);                         // valid lanes 0..15
                const int g3 = lane & 3;
                float s3 = sb3[g3];
                #pragma unroll
                for (int q = 0; q < 4; q++)
                    s3 = fmaf(__shfl(h2v, g3 * 4 + q, 64), sW3[g3 * 4 + q], s3);
                if (lane < 4) escale[lane] = sigmoidf_(s3);
            }
            __syncthreads();   // escale visible

            // state update: thread u < 128 owns h = 2u, 2u+1
            if (tid < 128) {
                const int h0u = 2 * tid;
                const float e0 = escale[0], e1 = escale[1], e2 = escale[2], e3 = escale[3];
                float2 gf = *(const float2*)&gatesv[0 * 256 + h0u];
                float2 gi = *(const float2*)&gatesv[1 * 256 + h0u];
                float2 gg2 = *(const float2*)&gatesv[2 * 256 + h0u];
                float2 go = *(const float2*)&gatesv[3 * 256 + h0u];
                float f0 = gf.x * e0, f1 = gf.y * e0;
                float i0 = gi.x * e1, i1 = gi.y * e1;
                float q0 = gg2.x * e2, q1 = gg2.y * e2;
                float o0 = go.x * e3, o1 = go.y * e3;
                cst0 = fmaf(f0, cst0, i0 * q0);
                cst1 = fmaf(f1, cst1, i1 * q1);
                hlast0 = o0 * tanhf_(cst0);
                hlast1 = o1 * tanhf_(cst1);
                combh2[tid] = packh2(hlast0, hlast1);
                *(float2*)&out[((size_t)t * BATCH + b) * H_DIM + h0u] =
                    make_float2(hlast0, hlast1);
            }
            __syncthreads();   // combh2 visible for next step / next pre-phase
        }
    }

    if (tid < 128) {
        const size_t st = (size_t)T_STEPS * BATCH * H_DIM;
        *(float2*)&out[st + (size_t)b * H_DIM + 2 * tid] = make_float2(hlast0, hlast1);
        *(float2*)&out[st + (size_t)BATCH * H_DIM + (size_t)b * H_DIM + 2 * tid] =
            make_float2(cst0, cst1);
    }
}

extern "C" void kernel_launch(void* const* d_in, const int* in_sizes, int n_in,
                              void* d_out, int out_size, void* d_ws, size_t ws_size,
                              hipStream_t stream) {
    const float* x     = (const float*)d_in[0];
    const float* Wf    = (const float*)d_in[1];
    const float* bf    = (const float*)d_in[2];
    const float* Wi    = (const float*)d_in[3];
    const float* bi    = (const float*)d_in[4];
    const float* Wg    = (const float*)d_in[5];
    const float* bg    = (const float*)d_in[6];
    const float* Wo    = (const float*)d_in[7];
    const float* bo    = (const float*)d_in[8];
    const float* estW1 = (const float*)d_in[9];
    const float* estb1 = (const float*)d_in[10];
    const float* estW2 = (const float*)d_in[11];
    const float* estb2 = (const float*)d_in[12];
    const float* estW3 = (const float*)d_in[13];
    const float* estb3 = (const float*)d_in[14];

    unsigned* WX2   = (unsigned*)d_ws;        // 512 KB
    unsigned* WHreg = WX2 + 128 * 1024;       // 256 KB
    unsigned* WHstr = WHreg + 64 * 1024;      // 256 KB
    float*    biasc = (float*)(WHstr + 64 * 1024);  // 4 KB

    prep_kernel<<<512, 256, 0, stream>>>(Wf, Wi, Wg, Wo, bf, bi, bg, bo,
                                         WX2, WHreg, WHstr, biasc);
    qlstm_kernel<<<BATCH, 512, 0, stream>>>(x, WX2, WHreg, WHstr, biasc,
                                            estW1, estb1, estW2, estb2, estW3, estb3,
                                            (float*)d_out);
}